// Round 2
// baseline (2530.788 us; speedup 1.0000x reference)
//
#include <hip/hip_runtime.h>

typedef unsigned short u16t;
typedef unsigned short us8 __attribute__((ext_vector_type(8)));
typedef unsigned short us4 __attribute__((ext_vector_type(4)));
typedef float f4 __attribute__((ext_vector_type(4)));

#define BB 2
#define TT 2048
#define CC 2048
#define HH 16
#define KVHN 4
#define DD 128
#define EPSV 1.1920929e-07f
#define SCALE 0.08838834764831845f

__device__ __forceinline__ float b2f(u16t u) {
    union { unsigned int i; float f; } x; x.i = ((unsigned int)u) << 16; return x.f;
}
__device__ __forceinline__ u16t f2b(float f) {
    union { float f; unsigned int i; } x; x.f = f;
    unsigned int r = x.i + 0x7fffu + ((x.i >> 16) & 1u);
    return (u16t)(r >> 16);
}
__device__ __forceinline__ f4 cvt4(us4 u) {
    f4 r; r[0] = b2f(u[0]); r[1] = b2f(u[1]); r[2] = b2f(u[2]); r[3] = b2f(u[3]); return r;
}

// ---------------- Kernel 1: QKV GEMM + RoPE + RMSNorm ----------------
// Z = x @ W^T for W = rows of [Wq;Wk;Wv] (3072 rows). BM=64, BN=128 (one head), BK=32.
// Inputs fp32; q/k/v written as bf16 head-major.
__global__ __launch_bounds__(256) void qkv_kernel(
    const float* __restrict__ x, const float* __restrict__ Wq,
    const float* __restrict__ Wk, const float* __restrict__ Wv,
    const float* __restrict__ cosp, const float* __restrict__ sinp,
    u16t* __restrict__ qws, u16t* __restrict__ kws, u16t* __restrict__ vws)
{
    __shared__ float smem[8192];          // staging (24KB used) / epilogue tile (32KB)
    float* As = smem;                     // [32][64]  k-major
    float* Bs = smem + 2048;              // [32][128] k-major

    const int tid = threadIdx.x;
    const int m0 = blockIdx.x * 64;
    const int n0 = blockIdx.y * 128;

    int type, head; const float* W;
    if (n0 < 2048)      { type = 0; head = n0 >> 7;          W = Wq + (size_t)n0 * CC; }
    else if (n0 < 2560) { type = 1; head = (n0 - 2048) >> 7; W = Wk + (size_t)(n0 - 2048) * CC; }
    else                { type = 2; head = (n0 - 2560) >> 7; W = Wv + (size_t)(n0 - 2560) * CC; }

    const int ty = tid >> 4, tx = tid & 15;
    const int arow = tid >> 2, acol = (tid & 3) * 8;   // A: 64 rows x 32 k
    const int brow = tid >> 1, bcol = (tid & 1) * 16;  // B: 128 rows x 32 k

    float acc[4][8];
    #pragma unroll
    for (int i = 0; i < 4; ++i)
        #pragma unroll
        for (int j = 0; j < 8; ++j) acc[i][j] = 0.f;

    for (int k0 = 0; k0 < CC; k0 += 32) {
        f4 av0 = *reinterpret_cast<const f4*>(x + (size_t)(m0 + arow) * CC + k0 + acol);
        f4 av1 = *reinterpret_cast<const f4*>(x + (size_t)(m0 + arow) * CC + k0 + acol + 4);
        f4 bv0 = *reinterpret_cast<const f4*>(W + (size_t)brow * CC + k0 + bcol);
        f4 bv1 = *reinterpret_cast<const f4*>(W + (size_t)brow * CC + k0 + bcol + 4);
        f4 bv2 = *reinterpret_cast<const f4*>(W + (size_t)brow * CC + k0 + bcol + 8);
        f4 bv3 = *reinterpret_cast<const f4*>(W + (size_t)brow * CC + k0 + bcol + 12);
        __syncthreads();
        #pragma unroll
        for (int q = 0; q < 4; ++q) {
            As[(acol + q) * 64 + arow]     = av0[q];
            As[(acol + 4 + q) * 64 + arow] = av1[q];
            Bs[(bcol + q) * 128 + brow]      = bv0[q];
            Bs[(bcol + 4 + q) * 128 + brow]  = bv1[q];
            Bs[(bcol + 8 + q) * 128 + brow]  = bv2[q];
            Bs[(bcol + 12 + q) * 128 + brow] = bv3[q];
        }
        __syncthreads();
        #pragma unroll 8
        for (int kk = 0; kk < 32; ++kk) {
            f4 a  = *reinterpret_cast<const f4*>(&As[kk * 64 + ty * 4]);
            f4 b0 = *reinterpret_cast<const f4*>(&Bs[kk * 128 + tx * 4]);
            f4 b1 = *reinterpret_cast<const f4*>(&Bs[kk * 128 + 64 + tx * 4]);
            #pragma unroll
            for (int i = 0; i < 4; ++i) {
                #pragma unroll
                for (int j = 0; j < 4; ++j) {
                    acc[i][j]     += a[i] * b0[j];
                    acc[i][j + 4] += a[i] * b1[j];
                }
            }
        }
    }

    if (type == 2) {
        // V: plain store, head-major [b, kvh, t, d]
        #pragma unroll
        for (int i = 0; i < 4; ++i) {
            int mb = m0 + ty * 4 + i;
            int b = mb >> 11, t = mb & (TT - 1);
            u16t* dst = vws + ((size_t)(b * KVHN + head) * TT + t) * DD;
            us4 o0, o1;
            #pragma unroll
            for (int j = 0; j < 4; ++j) { o0[j] = f2b(acc[i][j]); o1[j] = f2b(acc[i][j + 4]); }
            *reinterpret_cast<us4*>(dst + tx * 4) = o0;
            *reinterpret_cast<us4*>(dst + 64 + tx * 4) = o1;
        }
    } else {
        // Q/K: round-trip through LDS for RoPE + RMSNorm
        __syncthreads();
        #pragma unroll
        for (int i = 0; i < 4; ++i) {
            int r = ty * 4 + i;
            #pragma unroll
            for (int j = 0; j < 4; ++j) {
                smem[r * 128 + tx * 4 + j]      = acc[i][j];
                smem[r * 128 + 64 + tx * 4 + j] = acc[i][j + 4];
            }
        }
        __syncthreads();
        const int r = tid >> 2, g = tid & 3, c0 = g * 32;
        int mb = m0 + r;
        int b = mb >> 11, t = mb & (TT - 1);
        float vals[32]; float ss = 0.f;
        #pragma unroll
        for (int u = 0; u < 32; ++u) {
            int c = c0 + u;
            float zo;
            if (c < 64) {
                float z1 = smem[r * 128 + c];
                float z2 = smem[r * 128 + c + 64];
                float cs = cosp[t * 64 + c], sn = sinp[t * 64 + c];
                zo = z1 * cs + z2 * sn;
            } else {
                float z1 = smem[r * 128 + c - 64];
                float z2 = smem[r * 128 + c];
                float cs = cosp[t * 64 + c - 64], sn = sinp[t * 64 + c - 64];
                zo = -z1 * sn + z2 * cs;
            }
            vals[u] = zo; ss += zo * zo;
        }
        ss += __shfl_xor(ss, 1, 4);
        ss += __shfl_xor(ss, 2, 4);
        float rms = rsqrtf(ss * (1.f / 128.f) + EPSV);
        u16t* dst = (type == 0)
            ? qws + ((size_t)(b * HH + head) * TT + t) * DD + c0
            : kws + ((size_t)(b * KVHN + head) * TT + t) * DD + c0;
        #pragma unroll
        for (int u = 0; u < 32; u += 4) {
            us4 o;
            o[0] = f2b(vals[u] * rms);     o[1] = f2b(vals[u + 1] * rms);
            o[2] = f2b(vals[u + 2] * rms); o[3] = f2b(vals[u + 3] * rms);
            *reinterpret_cast<us4*>(dst + u) = o;
        }
    }
}

// ---------------- Kernel 2: causal flash attention (bf16 in/out) ----------------
// One block = (b, h, 64-query tile). K-tiles of 64, online softmax.
__global__ __launch_bounds__(256) void attn_kernel(
    const u16t* __restrict__ qws, const u16t* __restrict__ kws,
    const u16t* __restrict__ vws, u16t* __restrict__ yws)
{
    __shared__ u16t qs[64 * 132];   // bf16, pad 4 per row
    __shared__ u16t ks[64 * 132];
    __shared__ u16t vs[64 * 132];
    __shared__ u16t ps[64 * 68];    // P tile bf16

    const int tid = threadIdx.x;
    const int qt = blockIdx.x, h = blockIdx.y, b = blockIdx.z;
    const int q0 = qt * 64;
    const int kvh = h >> 2;
    const u16t* qbase = qws + ((size_t)(b * HH + h) * TT + q0) * DD;
    const u16t* kbase = kws + (size_t)(b * KVHN + kvh) * TT * DD;
    const u16t* vbase = vws + (size_t)(b * KVHN + kvh) * TT * DD;
    const int ty = tid >> 4, tx = tid & 15;

    // stage Q tile (coalesced, into padded rows)
    #pragma unroll
    for (int u = 0; u < 4; ++u) {
        int e = u * 2048 + tid * 8;
        int row = e >> 7, col = e & 127;
        const us4* gp = reinterpret_cast<const us4*>(qbase + e);
        *reinterpret_cast<us4*>(&qs[row * 132 + col])     = gp[0];
        *reinterpret_cast<us4*>(&qs[row * 132 + col + 4]) = gp[1];
    }

    float m_[4], l_[4], o_[4][8];
    #pragma unroll
    for (int i = 0; i < 4; ++i) {
        m_[i] = -__builtin_inff(); l_[i] = 0.f;
        #pragma unroll
        for (int j = 0; j < 8; ++j) o_[i][j] = 0.f;
    }

    for (int kt = 0; kt <= qt; ++kt) {
        const int k0 = kt * 64;
        __syncthreads();   // previous PV done before restaging
        #pragma unroll
        for (int u = 0; u < 4; ++u) {
            int e = u * 2048 + tid * 8;
            int row = e >> 7, col = e & 127;
            const us4* kp = reinterpret_cast<const us4*>(kbase + (size_t)k0 * DD + e);
            *reinterpret_cast<us4*>(&ks[row * 132 + col])     = kp[0];
            *reinterpret_cast<us4*>(&ks[row * 132 + col + 4]) = kp[1];
            const us4* vp = reinterpret_cast<const us4*>(vbase + (size_t)k0 * DD + e);
            *reinterpret_cast<us4*>(&vs[row * 132 + col])     = vp[0];
            *reinterpret_cast<us4*>(&vs[row * 132 + col + 4]) = vp[1];
        }
        __syncthreads();

        // S = Q K^T tile: rows ty*4+i, cols tx+16j (stride-16 to dodge bank conflicts)
        float s[4][4];
        #pragma unroll
        for (int i = 0; i < 4; ++i)
            #pragma unroll
            for (int j = 0; j < 4; ++j) s[i][j] = 0.f;
        #pragma unroll 4
        for (int d0 = 0; d0 < 128; d0 += 4) {
            f4 qv[4], kv[4];
            #pragma unroll
            for (int i = 0; i < 4; ++i)
                qv[i] = cvt4(*reinterpret_cast<const us4*>(&qs[(ty * 4 + i) * 132 + d0]));
            #pragma unroll
            for (int j = 0; j < 4; ++j)
                kv[j] = cvt4(*reinterpret_cast<const us4*>(&ks[(tx + 16 * j) * 132 + d0]));
            #pragma unroll
            for (int i = 0; i < 4; ++i)
                #pragma unroll
                for (int j = 0; j < 4; ++j)
                    s[i][j] += qv[i][0] * kv[j][0] + qv[i][1] * kv[j][1]
                             + qv[i][2] * kv[j][2] + qv[i][3] * kv[j][3];
        }

        // online softmax per row (16 lanes per row group)
        #pragma unroll
        for (int i = 0; i < 4; ++i) {
            int qi = q0 + ty * 4 + i;
            float sv[4];
            #pragma unroll
            for (int j = 0; j < 4; ++j) {
                int kj = k0 + tx + 16 * j;
                sv[j] = (kj <= qi) ? s[i][j] * SCALE : -__builtin_inff();
            }
            float mx = fmaxf(fmaxf(sv[0], sv[1]), fmaxf(sv[2], sv[3]));
            mx = fmaxf(mx, __shfl_xor(mx, 1, 16));
            mx = fmaxf(mx, __shfl_xor(mx, 2, 16));
            mx = fmaxf(mx, __shfl_xor(mx, 4, 16));
            mx = fmaxf(mx, __shfl_xor(mx, 8, 16));
            float mnew = fmaxf(m_[i], mx);
            float p[4], rs = 0.f;
            #pragma unroll
            for (int j = 0; j < 4; ++j) { p[j] = __expf(sv[j] - mnew); rs += p[j]; }
            rs += __shfl_xor(rs, 1, 16);
            rs += __shfl_xor(rs, 2, 16);
            rs += __shfl_xor(rs, 4, 16);
            rs += __shfl_xor(rs, 8, 16);
            float alpha = __expf(m_[i] - mnew);
            l_[i] = l_[i] * alpha + rs;
            m_[i] = mnew;
            #pragma unroll
            for (int j = 0; j < 8; ++j) o_[i][j] *= alpha;
            #pragma unroll
            for (int j = 0; j < 4; ++j) ps[(ty * 4 + i) * 68 + tx + 16 * j] = f2b(p[j]);
        }
        __syncthreads();

        // O += P V
        #pragma unroll 8
        for (int kk = 0; kk < 64; ++kk) {
            float pr[4];
            #pragma unroll
            for (int i = 0; i < 4; ++i) pr[i] = b2f(ps[(ty * 4 + i) * 68 + kk]);
            f4 v0 = cvt4(*reinterpret_cast<const us4*>(&vs[kk * 132 + tx * 4]));
            f4 v1 = cvt4(*reinterpret_cast<const us4*>(&vs[kk * 132 + 64 + tx * 4]));
            #pragma unroll
            for (int i = 0; i < 4; ++i)
                #pragma unroll
                for (int j = 0; j < 4; ++j) {
                    o_[i][j]     += pr[i] * v0[j];
                    o_[i][j + 4] += pr[i] * v1[j];
                }
        }
    }

    // normalize and store y in [b, t, h*D] layout (bf16)
    #pragma unroll
    for (int i = 0; i < 4; ++i) {
        float inv = 1.f / l_[i];
        int qi = q0 + ty * 4 + i;
        u16t* dst = yws + ((size_t)(b * TT + qi)) * (HH * DD) + h * DD;
        us4 o0, o1;
        #pragma unroll
        for (int j = 0; j < 4; ++j) { o0[j] = f2b(o_[i][j] * inv); o1[j] = f2b(o_[i][j + 4] * inv); }
        *reinterpret_cast<us4*>(dst + tx * 4) = o0;
        *reinterpret_cast<us4*>(dst + 64 + tx * 4) = o1;
    }
}

// ---------------- Kernel 3: output projection (y bf16, Wo fp32, out fp32) ----------------
__global__ __launch_bounds__(256) void oproj_kernel(
    const u16t* __restrict__ y, const float* __restrict__ Wo, float* __restrict__ out)
{
    __shared__ float smem[6144];
    float* As = smem;            // [32][64]
    float* Bs = smem + 2048;     // [32][128]

    const int tid = threadIdx.x;
    const int m0 = blockIdx.x * 64;
    const int n0 = blockIdx.y * 128;
    const float* W = Wo + (size_t)n0 * CC;

    const int ty = tid >> 4, tx = tid & 15;
    const int arow = tid >> 2, acol = (tid & 3) * 8;
    const int brow = tid >> 1, bcol = (tid & 1) * 16;

    float acc[4][8];
    #pragma unroll
    for (int i = 0; i < 4; ++i)
        #pragma unroll
        for (int j = 0; j < 8; ++j) acc[i][j] = 0.f;

    for (int k0 = 0; k0 < CC; k0 += 32) {
        us8 av  = *reinterpret_cast<const us8*>(y + (size_t)(m0 + arow) * CC + k0 + acol);
        f4 bv0 = *reinterpret_cast<const f4*>(W + (size_t)brow * CC + k0 + bcol);
        f4 bv1 = *reinterpret_cast<const f4*>(W + (size_t)brow * CC + k0 + bcol + 4);
        f4 bv2 = *reinterpret_cast<const f4*>(W + (size_t)brow * CC + k0 + bcol + 8);
        f4 bv3 = *reinterpret_cast<const f4*>(W + (size_t)brow * CC + k0 + bcol + 12);
        __syncthreads();
        #pragma unroll
        for (int q = 0; q < 8; ++q) As[(acol + q) * 64 + arow] = b2f(av[q]);
        #pragma unroll
        for (int q = 0; q < 4; ++q) {
            Bs[(bcol + q) * 128 + brow]      = bv0[q];
            Bs[(bcol + 4 + q) * 128 + brow]  = bv1[q];
            Bs[(bcol + 8 + q) * 128 + brow]  = bv2[q];
            Bs[(bcol + 12 + q) * 128 + brow] = bv3[q];
        }
        __syncthreads();
        #pragma unroll 8
        for (int kk = 0; kk < 32; ++kk) {
            f4 a  = *reinterpret_cast<const f4*>(&As[kk * 64 + ty * 4]);
            f4 b0 = *reinterpret_cast<const f4*>(&Bs[kk * 128 + tx * 4]);
            f4 b1 = *reinterpret_cast<const f4*>(&Bs[kk * 128 + 64 + tx * 4]);
            #pragma unroll
            for (int i = 0; i < 4; ++i) {
                #pragma unroll
                for (int j = 0; j < 4; ++j) {
                    acc[i][j]     += a[i] * b0[j];
                    acc[i][j + 4] += a[i] * b1[j];
                }
            }
        }
    }

    #pragma unroll
    for (int i = 0; i < 4; ++i) {
        int mb = m0 + ty * 4 + i;
        float* dst = out + (size_t)mb * CC + n0;
        f4 o0, o1;
        #pragma unroll
        for (int j = 0; j < 4; ++j) { o0[j] = acc[i][j]; o1[j] = acc[i][j + 4]; }
        *reinterpret_cast<f4*>(dst + tx * 4) = o0;
        *reinterpret_cast<f4*>(dst + 64 + tx * 4) = o1;
    }
}

extern "C" void kernel_launch(void* const* d_in, const int* in_sizes, int n_in,
                              void* d_out, int out_size, void* d_ws, size_t ws_size,
                              hipStream_t stream) {
    const float* x    = (const float*)d_in[0];
    const float* cosp = (const float*)d_in[1];
    const float* sinp = (const float*)d_in[2];
    const float* Wq   = (const float*)d_in[3];
    const float* Wk   = (const float*)d_in[4];
    const float* Wv   = (const float*)d_in[5];
    const float* Wo   = (const float*)d_in[6];

    u16t* ws  = (u16t*)d_ws;
    u16t* qws = ws;                                       // [B,H,T,D]   8388608
    u16t* kws = qws + (size_t)BB * HH * TT * DD;          // [B,KVH,T,D] 2097152
    u16t* vws = kws + (size_t)BB * KVHN * TT * DD;        // [B,KVH,T,D] 2097152
    u16t* yws = vws + (size_t)BB * KVHN * TT * DD;        // [B,T,H*D]   8388608
    float* out = (float*)d_out;

    qkv_kernel<<<dim3(64, 24), 256, 0, stream>>>(x, Wq, Wk, Wv, cosp, sinp, qws, kws, vws);
    attn_kernel<<<dim3(32, 16, 2), 256, 0, stream>>>(qws, kws, vws, yws);
    oproj_kernel<<<dim3(64, 16), 256, 0, stream>>>(yws, Wo, out);
}

// Round 3
// 608.240 us; speedup vs baseline: 4.1608x; 4.1608x over previous
//
#include <hip/hip_runtime.h>
#include <hip/hip_bf16.h>

typedef unsigned short u16t;
typedef unsigned int   u32t;
typedef float  f32x4 __attribute__((ext_vector_type(4)));
typedef short  s16x8 __attribute__((ext_vector_type(8)));
typedef unsigned int u32x4 __attribute__((ext_vector_type(4)));
typedef float  f4 __attribute__((ext_vector_type(4)));

#define BB 2
#define TT 2048
#define CC 2048
#define HH 16
#define KVHN 4
#define DD 128
#define EPSV 1.1920929e-07f
#define SCALE 0.08838834764831845f
#define NINF (-__builtin_inff())
#define LDA 40   // GEMM LDS row stride (bf16): pad 32->40 => <=2-way bank conflicts

__device__ __forceinline__ float b2f(u16t u){ union{u32t i; float f;} x; x.i=((u32t)u)<<16; return x.f; }
__device__ __forceinline__ u16t f2b(float f){ union{float f; u32t i;} x; x.f=f; u32t r = x.i + 0x7fffu + ((x.i>>16)&1u); return (u16t)(r>>16); }
__device__ __forceinline__ u32t pk2(float a, float b){
    __hip_bfloat162 h = __float22bfloat162_rn(make_float2(a,b));
    u32t r; __builtin_memcpy(&r,&h,4); return r;
}
__device__ __forceinline__ s16x8 ldf(const u16t* p){ s16x8 r; __builtin_memcpy(&r,p,16); return r; }
__device__ __forceinline__ void st16(u16t* p, u32x4 v){ __builtin_memcpy(p,&v,16); }
__device__ __forceinline__ u32x4 ldg16(const u16t* p){ u32x4 r; __builtin_memcpy(&r,p,16); return r; }

// ---------------- Kernel 1: QKV GEMM (MFMA) + RoPE + RMSNorm ----------------
// C = x @ W^T, W rows = [Wq;Wk;Wv]. Tile 128x128, BK=32. One N-block = one head.
__global__ __launch_bounds__(256) void qkv_kernel(
    const float* __restrict__ x, const float* __restrict__ Wq,
    const float* __restrict__ Wk, const float* __restrict__ Wv,
    const float* __restrict__ cosp, const float* __restrict__ sinp,
    u16t* __restrict__ qws, u16t* __restrict__ kws, u16t* __restrict__ vtw)
{
    __shared__ u16t lds[16896];   // 33792 B: staging As+Bs (20480) / epilogue Cs (33792)
    u16t* As = lds;               // [128][LDA]
    u16t* Bs = lds + 128*LDA;     // [128][LDA]

    const int tid = threadIdx.x;
    const int w = tid>>6, lane = tid&63, quad = lane>>4, l15 = lane&15;
    const int wm = (w>>1)*64, wn = (w&1)*64;
    const int m0 = blockIdx.x*128;
    const int n0 = blockIdx.y*128;

    int type, head; const float* W;
    if (n0 < 2048)      { type=0; head = n0>>7;        W = Wq + (size_t)n0*CC; }
    else if (n0 < 2560) { type=1; head = (n0-2048)>>7; W = Wk + (size_t)(n0-2048)*CC; }
    else                { type=2; head = (n0-2560)>>7; W = Wv + (size_t)(n0-2560)*CC; }

    const int srow = tid>>1, sc = (tid&1)*16;
    const float* ap = x + (size_t)(m0+srow)*CC + sc;
    const float* bp = W + (size_t)srow*CC + sc;

    f32x4 acc[4][4];
    #pragma unroll
    for (int i=0;i<4;++i)
        #pragma unroll
        for (int j=0;j<4;++j)
            #pragma unroll
            for (int r=0;r<4;++r) acc[i][j][r] = 0.f;

    for (int k0=0;k0<CC;k0+=32) {
        f4 a0 = *(const f4*)(ap+k0);    f4 a1 = *(const f4*)(ap+k0+4);
        f4 a2 = *(const f4*)(ap+k0+8);  f4 a3 = *(const f4*)(ap+k0+12);
        f4 b0 = *(const f4*)(bp+k0);    f4 b1 = *(const f4*)(bp+k0+4);
        f4 b2 = *(const f4*)(bp+k0+8);  f4 b3 = *(const f4*)(bp+k0+12);
        __syncthreads();
        u32x4 pa0 = { pk2(a0[0],a0[1]), pk2(a0[2],a0[3]), pk2(a1[0],a1[1]), pk2(a1[2],a1[3]) };
        u32x4 pa1 = { pk2(a2[0],a2[1]), pk2(a2[2],a2[3]), pk2(a3[0],a3[1]), pk2(a3[2],a3[3]) };
        u32x4 pb0 = { pk2(b0[0],b0[1]), pk2(b0[2],b0[3]), pk2(b1[0],b1[1]), pk2(b1[2],b1[3]) };
        u32x4 pb1 = { pk2(b2[0],b2[1]), pk2(b2[2],b2[3]), pk2(b3[0],b3[1]), pk2(b3[2],b3[3]) };
        st16(&As[srow*LDA+sc],   pa0); st16(&As[srow*LDA+sc+8], pa1);
        st16(&Bs[srow*LDA+sc],   pb0); st16(&Bs[srow*LDA+sc+8], pb1);
        __syncthreads();
        s16x8 af[4], bf[4];
        #pragma unroll
        for (int mi=0;mi<4;++mi) af[mi] = ldf(&As[(wm+mi*16+l15)*LDA + quad*8]);
        #pragma unroll
        for (int ni=0;ni<4;++ni) bf[ni] = ldf(&Bs[(wn+ni*16+l15)*LDA + quad*8]);
        #pragma unroll
        for (int mi=0;mi<4;++mi)
            #pragma unroll
            for (int ni=0;ni<4;++ni)
                acc[mi][ni] = __builtin_amdgcn_mfma_f32_16x16x32_bf16(af[mi], bf[ni], acc[mi][ni], 0,0,0);
    }

    const int bb = m0>>11, tb0 = m0&2047;

    if (type==2) {
        // V: store transposed vt[b][kvh][d][t]
        u16t* vb = vtw + (size_t)(bb*KVHN+head)*DD*TT;
        #pragma unroll
        for (int mi=0;mi<4;++mi){
            int t = tb0 + wm + mi*16 + quad*4;
            #pragma unroll
            for (int ni=0;ni<4;++ni){
                int d = wn + ni*16 + l15;
                u16t o[4];
                #pragma unroll
                for (int r=0;r<4;++r) o[r] = f2b(acc[mi][ni][r]);
                __builtin_memcpy(vb + (size_t)d*TT + t, o, 8);
            }
        }
    } else {
        __syncthreads();
        u16t* Cs = lds;   // [128][132] bf16
        #pragma unroll
        for (int mi=0;mi<4;++mi)
            #pragma unroll
            for (int ni=0;ni<4;++ni)
                #pragma unroll
                for (int r=0;r<4;++r)
                    Cs[(wm+mi*16+quad*4+r)*132 + wn+ni*16+l15] = f2b(acc[mi][ni][r]);
        __syncthreads();
        const int r = tid>>1, g = tid&1;
        const int t = tb0 + r;
        float vals[64]; float ss=0.f;
        const f4* cp = (const f4*)(cosp + t*64);
        const f4* sp = (const f4*)(sinp + t*64);
        #pragma unroll
        for (int j4=0;j4<16;++j4){
            f4 cs = cp[j4], sn = sp[j4];
            #pragma unroll
            for (int u=0;u<4;++u){
                int j = j4*4+u;
                float z1 = b2f(Cs[r*132 + j]);
                float z2 = b2f(Cs[r*132 + 64 + j]);
                float zo = g ? (z2*cs[u] - z1*sn[u]) : (z1*cs[u] + z2*sn[u]);
                vals[j]=zo; ss += zo*zo;
            }
        }
        ss += __shfl_xor(ss, 1);
        float rms = rsqrtf(ss*(1.f/128.f)+EPSV);
        u16t* dst = (type==0 ? qws + ((size_t)(bb*HH+head)*TT + t)*DD
                             : kws + ((size_t)(bb*KVHN+head)*TT + t)*DD) + g*64;
        #pragma unroll
        for (int j=0;j<64;j+=8){
            u32x4 o = { pk2(vals[j]*rms,   vals[j+1]*rms), pk2(vals[j+2]*rms, vals[j+3]*rms),
                        pk2(vals[j+4]*rms, vals[j+5]*rms), pk2(vals[j+6]*rms, vals[j+7]*rms) };
            st16(dst+j, o);
        }
    }
}

// ---------------- Kernel 2: causal flash attention (MFMA) ----------------
// Block = (qtile 128, h, b); 4 waves x 32 queries; K-tiles of 64.
__global__ __launch_bounds__(256) void attn_kernel(
    const u16t* __restrict__ qws, const u16t* __restrict__ kws,
    const u16t* __restrict__ vtw, u16t* __restrict__ yws)
{
    __shared__ u16t lds[27136];       // 54272 B
    u16t* Qs = lds;                   // [128][136] (dead after frag load)
    u16t* Ks = lds;                   // [64][136]
    u16t* Vt = lds + 8704;            // [128][72]  V^T tile: [d][kv]
    u16t* Ps = lds + 17920;           // [128][72]  per-wave P slices

    const int tid = threadIdx.x;
    const int w = tid>>6, lane = tid&63, quad = lane>>4, l15 = lane&15;
    const int qti = 15 - blockIdx.x;  // long blocks dispatch first
    const int q0 = qti*128;
    const int h = blockIdx.y, b = blockIdx.z, kvh = h>>2;

    const u16t* qb = qws + ((size_t)(b*HH+h)*TT + q0)*DD;
    const u16t* kb = kws + (size_t)(b*KVHN+kvh)*TT*DD;
    const u16t* vb = vtw + (size_t)(b*KVHN+kvh)*DD*TT;

    {   // stage Q tile
        const int row = tid>>1, c = (tid&1)*64;
        #pragma unroll
        for (int u=0;u<8;++u)
            st16(&Qs[row*136 + c + u*8], ldg16(qb + (size_t)row*DD + c + u*8));
    }
    __syncthreads();
    s16x8 qf[2][4];
    #pragma unroll
    for (int mi=0;mi<2;++mi)
        #pragma unroll
        for (int kq=0;kq<4;++kq)
            qf[mi][kq] = ldf(&Qs[(w*32+mi*16+l15)*136 + kq*32 + quad*8]);

    f32x4 o_[2][8];
    float m_[2][4], l_[2][4];
    #pragma unroll
    for (int mi=0;mi<2;++mi){
        #pragma unroll
        for (int r=0;r<4;++r){ m_[mi][r] = NINF; l_[mi][r] = 0.f; }
        #pragma unroll
        for (int n8=0;n8<8;++n8)
            #pragma unroll
            for (int r=0;r<4;++r) o_[mi][n8][r] = 0.f;
    }

    const int nkt = (qti+1)*2;
    const int qwbase = q0 + w*32;

    for (int kt=0; kt<nkt; ++kt){
        const int k0 = kt*64;
        __syncthreads();   // protect Qs (iter0) / Ks,Vt readers (iter>0)
        {
            const int kv = tid>>2, c4 = (tid&3)*32;
            #pragma unroll
            for (int u=0;u<4;++u)
                st16(&Ks[kv*136 + c4 + u*8], ldg16(kb + (size_t)(k0+kv)*DD + c4 + u*8));
            const int d = tid>>1, c2 = (tid&1)*32;
            #pragma unroll
            for (int u=0;u<4;++u)
                st16(&Vt[d*72 + c2 + u*8], ldg16(vb + (size_t)d*TT + k0 + c2 + u*8));
        }
        __syncthreads();
        if (k0 > qwbase + 31) continue;   // wave-uniform: tile fully masked for this wave

        // S = Q K^T
        f32x4 s[2][4];
        #pragma unroll
        for (int mi=0;mi<2;++mi)
            #pragma unroll
            for (int ni=0;ni<4;++ni)
                #pragma unroll
                for (int r=0;r<4;++r) s[mi][ni][r] = 0.f;
        #pragma unroll
        for (int kq=0;kq<4;++kq){
            s16x8 kf[4];
            #pragma unroll
            for (int ni=0;ni<4;++ni) kf[ni] = ldf(&Ks[(ni*16+l15)*136 + kq*32 + quad*8]);
            #pragma unroll
            for (int mi=0;mi<2;++mi)
                #pragma unroll
                for (int ni=0;ni<4;++ni)
                    s[mi][ni] = __builtin_amdgcn_mfma_f32_16x16x32_bf16(qf[mi][kq], kf[ni], s[mi][ni], 0,0,0);
        }

        const bool need_mask = (k0 + 63) > qwbase;
        #pragma unroll
        for (int mi=0;mi<2;++mi){
            const int qrow = qwbase + mi*16 + quad*4;
            float sv[4][4];
            float mx[4] = {NINF,NINF,NINF,NINF};
            #pragma unroll
            for (int ni=0;ni<4;++ni){
                const int kcol = k0 + ni*16 + l15;
                #pragma unroll
                for (int r=0;r<4;++r){
                    float v = s[mi][ni][r]*SCALE;
                    if (need_mask && kcol > qrow + r) v = NINF;
                    sv[ni][r] = v;
                    mx[r] = fmaxf(mx[r], v);
                }
            }
            #pragma unroll
            for (int r=0;r<4;++r){
                float m = mx[r];
                m = fmaxf(m, __shfl_xor(m,1,16));
                m = fmaxf(m, __shfl_xor(m,2,16));
                m = fmaxf(m, __shfl_xor(m,4,16));
                m = fmaxf(m, __shfl_xor(m,8,16));
                float mnew = fmaxf(m_[mi][r], m);
                float alpha = __expf(m_[mi][r] - mnew);
                m_[mi][r] = mnew;
                float rs = 0.f;
                #pragma unroll
                for (int ni=0;ni<4;++ni){ float p = __expf(sv[ni][r]-mnew); sv[ni][r]=p; rs+=p; }
                rs += __shfl_xor(rs,1,16);
                rs += __shfl_xor(rs,2,16);
                rs += __shfl_xor(rs,4,16);
                rs += __shfl_xor(rs,8,16);
                l_[mi][r] = l_[mi][r]*alpha + rs;
                #pragma unroll
                for (int n8=0;n8<8;++n8) o_[mi][n8][r] *= alpha;
            }
            #pragma unroll
            for (int ni=0;ni<4;++ni)
                #pragma unroll
                for (int r=0;r<4;++r)
                    Ps[(w*32+mi*16+quad*4+r)*72 + ni*16 + l15] = f2b(sv[ni][r]);
        }

        // O += P V   (P round-trip is same-wave: DS in-order, no barrier needed)
        #pragma unroll
        for (int ks=0;ks<2;++ks){
            s16x8 pf[2];
            #pragma unroll
            for (int mi=0;mi<2;++mi)
                pf[mi] = ldf(&Ps[(w*32+mi*16+l15)*72 + ks*32 + quad*8]);
            #pragma unroll
            for (int n8=0;n8<8;++n8){
                s16x8 vf = ldf(&Vt[(n8*16+l15)*72 + ks*32 + quad*8]);
                #pragma unroll
                for (int mi=0;mi<2;++mi)
                    o_[mi][n8] = __builtin_amdgcn_mfma_f32_16x16x32_bf16(pf[mi], vf, o_[mi][n8], 0,0,0);
            }
        }
    }

    // epilogue: y[b][t][h*128+d]
    #pragma unroll
    for (int mi=0;mi<2;++mi){
        const int qrow = q0 + w*32 + mi*16 + quad*4;
        float inv[4];
        #pragma unroll
        for (int r=0;r<4;++r) inv[r] = 1.f/l_[mi][r];
        #pragma unroll
        for (int n8=0;n8<8;++n8)
            #pragma unroll
            for (int r=0;r<4;++r)
                yws[((size_t)(b*TT + qrow + r))*2048 + h*DD + n8*16 + l15] = f2b(o_[mi][n8][r]*inv[r]);
    }
}

// ---------------- Kernel 3: output projection (MFMA) ----------------
__global__ __launch_bounds__(256) void oproj_kernel(
    const u16t* __restrict__ y, const float* __restrict__ Wo, float* __restrict__ out)
{
    __shared__ u16t lds[10240];   // As+Bs
    u16t* As = lds;               // [128][LDA]
    u16t* Bs = lds + 128*LDA;

    const int tid = threadIdx.x;
    const int w = tid>>6, lane = tid&63, quad = lane>>4, l15 = lane&15;
    const int wm = (w>>1)*64, wn = (w&1)*64;
    const int m0 = blockIdx.x*128;
    const int n0 = blockIdx.y*128;

    const int srow = tid>>1, sc = (tid&1)*16;
    const u16t* ap = y + (size_t)(m0+srow)*CC + sc;
    const float* bp = Wo + (size_t)(n0+srow)*CC + sc;

    f32x4 acc[4][4];
    #pragma unroll
    for (int i=0;i<4;++i)
        #pragma unroll
        for (int j=0;j<4;++j)
            #pragma unroll
            for (int r=0;r<4;++r) acc[i][j][r] = 0.f;

    for (int k0=0;k0<CC;k0+=32) {
        u32x4 av0 = ldg16(ap+k0), av1 = ldg16(ap+k0+8);
        f4 b0 = *(const f4*)(bp+k0);    f4 b1 = *(const f4*)(bp+k0+4);
        f4 b2 = *(const f4*)(bp+k0+8);  f4 b3 = *(const f4*)(bp+k0+12);
        __syncthreads();
        u32x4 pb0 = { pk2(b0[0],b0[1]), pk2(b0[2],b0[3]), pk2(b1[0],b1[1]), pk2(b1[2],b1[3]) };
        u32x4 pb1 = { pk2(b2[0],b2[1]), pk2(b2[2],b2[3]), pk2(b3[0],b3[1]), pk2(b3[2],b3[3]) };
        st16(&As[srow*LDA+sc],   av0); st16(&As[srow*LDA+sc+8], av1);
        st16(&Bs[srow*LDA+sc],   pb0); st16(&Bs[srow*LDA+sc+8], pb1);
        __syncthreads();
        s16x8 af[4], bf[4];
        #pragma unroll
        for (int mi=0;mi<4;++mi) af[mi] = ldf(&As[(wm+mi*16+l15)*LDA + quad*8]);
        #pragma unroll
        for (int ni=0;ni<4;++ni) bf[ni] = ldf(&Bs[(wn+ni*16+l15)*LDA + quad*8]);
        #pragma unroll
        for (int mi=0;mi<4;++mi)
            #pragma unroll
            for (int ni=0;ni<4;++ni)
                acc[mi][ni] = __builtin_amdgcn_mfma_f32_16x16x32_bf16(af[mi], bf[ni], acc[mi][ni], 0,0,0);
    }

    #pragma unroll
    for (int mi=0;mi<4;++mi){
        const int m = m0 + wm + mi*16 + quad*4;
        #pragma unroll
        for (int ni=0;ni<4;++ni){
            const int n = n0 + wn + ni*16 + l15;
            #pragma unroll
            for (int r=0;r<4;++r)
                out[(size_t)(m+r)*CC + n] = acc[mi][ni][r];
        }
    }
}

extern "C" void kernel_launch(void* const* d_in, const int* in_sizes, int n_in,
                              void* d_out, int out_size, void* d_ws, size_t ws_size,
                              hipStream_t stream) {
    const float* x    = (const float*)d_in[0];
    const float* cosp = (const float*)d_in[1];
    const float* sinp = (const float*)d_in[2];
    const float* Wq   = (const float*)d_in[3];
    const float* Wk   = (const float*)d_in[4];
    const float* Wv   = (const float*)d_in[5];
    const float* Wo   = (const float*)d_in[6];

    u16t* ws  = (u16t*)d_ws;
    u16t* qws = ws;                                       // [B,H,T,D]    8388608
    u16t* kws = qws + (size_t)BB * HH * TT * DD;          // [B,KVH,T,D]  2097152
    u16t* vtw = kws + (size_t)BB * KVHN * TT * DD;        // [B,KVH,D,T]  2097152
    u16t* yws = vtw + (size_t)BB * KVHN * TT * DD;        // [B,T,H*D]    8388608
    float* out = (float*)d_out;

    qkv_kernel<<<dim3(32, 24), 256, 0, stream>>>(x, Wq, Wk, Wv, cosp, sinp, qws, kws, vtw);
    attn_kernel<<<dim3(16, 16, 2), 256, 0, stream>>>(qws, kws, vtw, yws);
    oproj_kernel<<<dim3(32, 16), 256, 0, stream>>>(yws, Wo, out);
}

// Round 4
// 398.054 us; speedup vs baseline: 6.3579x; 1.5280x over previous
//
#include <hip/hip_runtime.h>
#include <hip/hip_bf16.h>

typedef unsigned short u16t;
typedef unsigned int   u32t;
typedef float  f32x4 __attribute__((ext_vector_type(4)));
typedef short  s16x8 __attribute__((ext_vector_type(8)));
typedef unsigned int u32x4 __attribute__((ext_vector_type(4)));
typedef float  f4 __attribute__((ext_vector_type(4)));

#define BB 2
#define TT 2048
#define CC 2048
#define HH 16
#define KVHN 4
#define DD 128
#define EPSV 1.1920929e-07f
#define SCALE 0.08838834764831845f
#define MFIX 12.0f   // fixed softmax max: |q.k|*SCALE <= sqrt(128)*(1+bf16 err) < 11.5

__device__ __forceinline__ float b2f(u16t u){ union{u32t i; float f;} x; x.i=((u32t)u)<<16; return x.f; }
__device__ __forceinline__ u16t f2b(float f){ union{float f; u32t i;} x; x.f=f; u32t r = x.i + 0x7fffu + ((x.i>>16)&1u); return (u16t)(r>>16); }
__device__ __forceinline__ u32t pk2(float a, float b){
    __hip_bfloat162 h = __float22bfloat162_rn(make_float2(a,b));
    u32t r; __builtin_memcpy(&r,&h,4); return r;
}
__device__ __forceinline__ s16x8 ldf(const u16t* p){ s16x8 r; __builtin_memcpy(&r,p,16); return r; }
__device__ __forceinline__ void st16(u16t* p, u32x4 v){ __builtin_memcpy(p,&v,16); }
__device__ __forceinline__ u32x4 ldg16(const u16t* p){ u32x4 r; __builtin_memcpy(&r,p,16); return r; }

// async global->LDS, 16B per lane; LDS dest = wave-uniform base + lane*16
typedef const __attribute__((address_space(1))) unsigned int ga_u32;
typedef __attribute__((address_space(3))) unsigned int ls_u32;
__device__ __forceinline__ void gl16(const u16t* g, u16t* l) {
    __builtin_amdgcn_global_load_lds((ga_u32*)(unsigned long long)(g),
                                     (ls_u32*)(unsigned int)(unsigned long long)(l),
                                     16, 0, 0);
}

// ---------------- Kernel 0: fp32 -> bf16 conversion ----------------
// segments (in 8-elem groups): x 1048576 | wq 524288 | wk 131072 | wv 131072 | wo 524288
__global__ __launch_bounds__(256) void cvt_kernel(
    const float* __restrict__ x,  const float* __restrict__ wq,
    const float* __restrict__ wk, const float* __restrict__ wv,
    const float* __restrict__ wo,
    u16t* __restrict__ xb, u16t* __restrict__ wqb, u16t* __restrict__ wkb,
    u16t* __restrict__ wvb, u16t* __restrict__ wob)
{
    size_t g = (size_t)blockIdx.x * 256 + threadIdx.x;
    const float* src; u16t* dst; size_t off;
    if      (g < 1048576) { src = x;  dst = xb;  off = g; }
    else if (g < 1572864) { src = wq; dst = wqb; off = g - 1048576; }
    else if (g < 1703936) { src = wk; dst = wkb; off = g - 1572864; }
    else if (g < 1835008) { src = wv; dst = wvb; off = g - 1703936; }
    else                  { src = wo; dst = wob; off = g - 1835008; }
    f4 a = *(const f4*)(src + off*8);
    f4 b = *(const f4*)(src + off*8 + 4);
    u32x4 o = { pk2(a[0],a[1]), pk2(a[2],a[3]), pk2(b[0],b[1]), pk2(b[2],b[3]) };
    st16(dst + off*8, o);
}

// ---------------- Kernel 1: QKV GEMM (MFMA, global_load_lds) + RoPE + RMSNorm ----------------
// C = xb @ W^T, W rows = [Wq;Wk;Wv] bf16. Tile 128x128, BK=32, unpadded [row][32] LDS.
__global__ __launch_bounds__(256) void qkv_kernel(
    const u16t* __restrict__ xb, const u16t* __restrict__ wqb,
    const u16t* __restrict__ wkb, const u16t* __restrict__ wvb,
    const float* __restrict__ cosp, const float* __restrict__ sinp,
    u16t* __restrict__ qws, u16t* __restrict__ kws, u16t* __restrict__ vtw)
{
    __shared__ u16t lds[16896];   // staging As+Bs (8192 elems) / epilogue Cs (16896 elems)
    u16t* As = lds;               // [128][32]
    u16t* Bs = lds + 4096;        // [128][32]

    const int tid = threadIdx.x;
    const int w = tid>>6, lane = tid&63, quad = lane>>4, l15 = lane&15;
    const int wm = (w>>1)*64, wn = (w&1)*64;
    const int m0 = blockIdx.x*128;
    const int n0 = blockIdx.y*128;

    int type, head; const u16t* W;
    if (n0 < 2048)      { type=0; head = n0>>7;        W = wqb + (size_t)n0*CC; }
    else if (n0 < 2560) { type=1; head = (n0-2048)>>7; W = wkb + (size_t)(n0-2048)*CC; }
    else                { type=2; head = (n0-2560)>>7; W = wvb + (size_t)(n0-2560)*CC; }

    // staging: wave w covers flat elems [w*1024, w*1024+1024) of each 4096-elem tile
    const int e0 = w*1024 + lane*8, e1 = e0 + 512;
    const int ar0 = e0>>5, ac0 = e0&31, ar1 = e1>>5, ac1 = e1&31;
    const u16t* gA0 = xb + (size_t)(m0+ar0)*CC + ac0;
    const u16t* gA1 = xb + (size_t)(m0+ar1)*CC + ac1;
    const u16t* gB0 = W + (size_t)ar0*CC + ac0;
    const u16t* gB1 = W + (size_t)ar1*CC + ac1;

    f32x4 acc[4][4];
    #pragma unroll
    for (int i=0;i<4;++i)
        #pragma unroll
        for (int j=0;j<4;++j)
            #pragma unroll
            for (int r=0;r<4;++r) acc[i][j][r] = 0.f;

    for (int k0=0;k0<CC;k0+=32) {
        __syncthreads();
        gl16(gA0 + k0, &As[e0]);
        gl16(gA1 + k0, &As[e1]);
        gl16(gB0 + k0, &Bs[e0]);
        gl16(gB1 + k0, &Bs[e1]);
        __syncthreads();
        s16x8 af[4], bf[4];
        #pragma unroll
        for (int mi=0;mi<4;++mi) af[mi] = ldf(&As[(wm+mi*16+l15)*32 + quad*8]);
        #pragma unroll
        for (int ni=0;ni<4;++ni) bf[ni] = ldf(&Bs[(wn+ni*16+l15)*32 + quad*8]);
        #pragma unroll
        for (int mi=0;mi<4;++mi)
            #pragma unroll
            for (int ni=0;ni<4;++ni)
                acc[mi][ni] = __builtin_amdgcn_mfma_f32_16x16x32_bf16(af[mi], bf[ni], acc[mi][ni], 0,0,0);
    }

    const int bb = m0>>11, tb0 = m0&2047;

    if (type==2) {
        // V: store transposed vt[b][kvh][d][t]
        u16t* vb = vtw + (size_t)(bb*KVHN+head)*DD*TT;
        #pragma unroll
        for (int mi=0;mi<4;++mi){
            int t = tb0 + wm + mi*16 + quad*4;
            #pragma unroll
            for (int ni=0;ni<4;++ni){
                int d = wn + ni*16 + l15;
                u16t o[4];
                #pragma unroll
                for (int r=0;r<4;++r) o[r] = f2b(acc[mi][ni][r]);
                __builtin_memcpy(vb + (size_t)d*TT + t, o, 8);
            }
        }
    } else {
        __syncthreads();
        u16t* Cs = lds;   // [128][132] bf16
        #pragma unroll
        for (int mi=0;mi<4;++mi)
            #pragma unroll
            for (int ni=0;ni<4;++ni)
                #pragma unroll
                for (int r=0;r<4;++r)
                    Cs[(wm+mi*16+quad*4+r)*132 + wn+ni*16+l15] = f2b(acc[mi][ni][r]);
        __syncthreads();
        const int r = tid>>1, g = tid&1;
        const int t = tb0 + r;
        float vals[64]; float ss=0.f;
        const f4* cp = (const f4*)(cosp + t*64);
        const f4* sp = (const f4*)(sinp + t*64);
        #pragma unroll
        for (int j4=0;j4<16;++j4){
            f4 cs = cp[j4], sn = sp[j4];
            #pragma unroll
            for (int u=0;u<4;++u){
                int j = j4*4+u;
                float z1 = b2f(Cs[r*132 + j]);
                float z2 = b2f(Cs[r*132 + 64 + j]);
                float zo = g ? (z2*cs[u] - z1*sn[u]) : (z1*cs[u] + z2*sn[u]);
                vals[j]=zo; ss += zo*zo;
            }
        }
        ss += __shfl_xor(ss, 1);
        float rms = rsqrtf(ss*(1.f/128.f)+EPSV);
        u16t* dst = (type==0 ? qws + ((size_t)(bb*HH+head)*TT + t)*DD
                             : kws + ((size_t)(bb*KVHN+head)*TT + t)*DD) + g*64;
        #pragma unroll
        for (int j=0;j<64;j+=8){
            u32x4 o = { pk2(vals[j]*rms,   vals[j+1]*rms), pk2(vals[j+2]*rms, vals[j+3]*rms),
                        pk2(vals[j+4]*rms, vals[j+5]*rms), pk2(vals[j+6]*rms, vals[j+7]*rms) };
            st16(dst+j, o);
        }
    }
}

// ---------------- Kernel 2: causal flash attention (MFMA, fixed-max softmax) ----------------
__global__ __launch_bounds__(256) void attn_kernel(
    const u16t* __restrict__ qws, const u16t* __restrict__ kws,
    const u16t* __restrict__ vtw, u16t* __restrict__ yws)
{
    __shared__ u16t lds[27136];       // 54272 B
    u16t* Qs = lds;                   // [128][136] (dead after frag load)
    u16t* Ks = lds;                   // [64][136]
    u16t* Vt = lds + 8704;            // [128][72]  V^T tile [d][kv]
    u16t* Ps = lds + 17920;           // [128][72]  per-wave P slices

    const int tid = threadIdx.x;
    const int w = tid>>6, lane = tid&63, quad = lane>>4, l15 = lane&15;
    const int qti = 15 - blockIdx.x;  // long blocks dispatch first
    const int q0 = qti*128;
    const int h = blockIdx.y, b = blockIdx.z, kvh = h>>2;

    const u16t* qb = qws + ((size_t)(b*HH+h)*TT + q0)*DD;
    const u16t* kb = kws + (size_t)(b*KVHN+kvh)*TT*DD;
    const u16t* vb = vtw + (size_t)(b*KVHN+kvh)*DD*TT;

    {   // stage Q tile
        const int row = tid>>1, c = (tid&1)*64;
        #pragma unroll
        for (int u=0;u<8;++u)
            st16(&Qs[row*136 + c + u*8], ldg16(qb + (size_t)row*DD + c + u*8));
    }
    __syncthreads();
    s16x8 qf[2][4];
    #pragma unroll
    for (int mi=0;mi<2;++mi)
        #pragma unroll
        for (int kq=0;kq<4;++kq)
            qf[mi][kq] = ldf(&Qs[(w*32+mi*16+l15)*136 + kq*32 + quad*8]);

    f32x4 o_[2][8];
    float l_[2][4];
    #pragma unroll
    for (int mi=0;mi<2;++mi){
        #pragma unroll
        for (int r=0;r<4;++r) l_[mi][r] = 0.f;
        #pragma unroll
        for (int n8=0;n8<8;++n8)
            #pragma unroll
            for (int r=0;r<4;++r) o_[mi][n8][r] = 0.f;
    }

    const int nkt = (qti+1)*2;
    const int qwbase = q0 + w*32;

    for (int kt=0; kt<nkt; ++kt){
        const int k0 = kt*64;
        __syncthreads();
        {
            const int kv = tid>>2, c4 = (tid&3)*32;
            #pragma unroll
            for (int u=0;u<4;++u)
                st16(&Ks[kv*136 + c4 + u*8], ldg16(kb + (size_t)(k0+kv)*DD + c4 + u*8));
            const int d = tid>>1, c2 = (tid&1)*32;
            #pragma unroll
            for (int u=0;u<4;++u)
                st16(&Vt[d*72 + c2 + u*8], ldg16(vb + (size_t)d*TT + k0 + c2 + u*8));
        }
        __syncthreads();
        if (k0 > qwbase + 31) continue;   // wave-uniform: fully masked for this wave

        // S = Q K^T
        f32x4 s[2][4];
        #pragma unroll
        for (int mi=0;mi<2;++mi)
            #pragma unroll
            for (int ni=0;ni<4;++ni)
                #pragma unroll
                for (int r=0;r<4;++r) s[mi][ni][r] = 0.f;
        #pragma unroll
        for (int kq=0;kq<4;++kq){
            s16x8 kf[4];
            #pragma unroll
            for (int ni=0;ni<4;++ni) kf[ni] = ldf(&Ks[(ni*16+l15)*136 + kq*32 + quad*8]);
            #pragma unroll
            for (int mi=0;mi<2;++mi)
                #pragma unroll
                for (int ni=0;ni<4;++ni)
                    s[mi][ni] = __builtin_amdgcn_mfma_f32_16x16x32_bf16(qf[mi][kq], kf[ni], s[mi][ni], 0,0,0);
        }

        // fixed-max softmax: p = exp(s*SCALE - 12); l accumulates per-lane partials
        const bool need_mask = (k0 + 63) > qwbase;
        #pragma unroll
        for (int mi=0;mi<2;++mi){
            const int qrow = qwbase + mi*16 + quad*4;
            #pragma unroll
            for (int ni=0;ni<4;++ni){
                const int kcol = k0 + ni*16 + l15;
                #pragma unroll
                for (int r=0;r<4;++r){
                    float p = __expf(__builtin_fmaf(s[mi][ni][r], SCALE, -MFIX));
                    if (need_mask && kcol > qrow + r) p = 0.f;
                    l_[mi][r] += p;
                    Ps[(w*32+mi*16+quad*4+r)*72 + ni*16 + l15] = f2b(p);
                }
            }
        }

        // O += P V  (same-wave LDS round-trip; DS ops in-order, no barrier)
        #pragma unroll
        for (int ks=0;ks<2;++ks){
            s16x8 pf[2];
            #pragma unroll
            for (int mi=0;mi<2;++mi)
                pf[mi] = ldf(&Ps[(w*32+mi*16+l15)*72 + ks*32 + quad*8]);
            #pragma unroll
            for (int n8=0;n8<8;++n8){
                s16x8 vf = ldf(&Vt[(n8*16+l15)*72 + ks*32 + quad*8]);
                #pragma unroll
                for (int mi=0;mi<2;++mi)
                    o_[mi][n8] = __builtin_amdgcn_mfma_f32_16x16x32_bf16(pf[mi], vf, o_[mi][n8], 0,0,0);
            }
        }
    }

    // epilogue: reduce l across the 16 col-lanes, normalize, store y[b][t][h*128+d]
    #pragma unroll
    for (int mi=0;mi<2;++mi){
        const int qrow = q0 + w*32 + mi*16 + quad*4;
        float inv[4];
        #pragma unroll
        for (int r=0;r<4;++r){
            float lt = l_[mi][r];
            lt += __shfl_xor(lt,1,16);
            lt += __shfl_xor(lt,2,16);
            lt += __shfl_xor(lt,4,16);
            lt += __shfl_xor(lt,8,16);
            inv[r] = 1.f/lt;
        }
        #pragma unroll
        for (int n8=0;n8<8;++n8)
            #pragma unroll
            for (int r=0;r<4;++r)
                yws[((size_t)(b*TT + qrow + r))*2048 + h*DD + n8*16 + l15] = f2b(o_[mi][n8][r]*inv[r]);
    }
}

// ---------------- Kernel 3: output projection (MFMA, global_load_lds) ----------------
__global__ __launch_bounds__(256) void oproj_kernel(
    const u16t* __restrict__ y, const u16t* __restrict__ wob, float* __restrict__ out)
{
    __shared__ u16t lds[8192];
    u16t* As = lds;               // [128][32]
    u16t* Bs = lds + 4096;

    const int tid = threadIdx.x;
    const int w = tid>>6, lane = tid&63, quad = lane>>4, l15 = lane&15;
    const int wm = (w>>1)*64, wn = (w&1)*64;
    const int m0 = blockIdx.x*128;
    const int n0 = blockIdx.y*128;

    const int e0 = w*1024 + lane*8, e1 = e0 + 512;
    const int ar0 = e0>>5, ac0 = e0&31, ar1 = e1>>5, ac1 = e1&31;
    const u16t* gA0 = y + (size_t)(m0+ar0)*CC + ac0;
    const u16t* gA1 = y + (size_t)(m0+ar1)*CC + ac1;
    const u16t* gB0 = wob + (size_t)(n0+ar0)*CC + ac0;
    const u16t* gB1 = wob + (size_t)(n0+ar1)*CC + ac1;

    f32x4 acc[4][4];
    #pragma unroll
    for (int i=0;i<4;++i)
        #pragma unroll
        for (int j=0;j<4;++j)
            #pragma unroll
            for (int r=0;r<4;++r) acc[i][j][r] = 0.f;

    for (int k0=0;k0<CC;k0+=32) {
        __syncthreads();
        gl16(gA0 + k0, &As[e0]);
        gl16(gA1 + k0, &As[e1]);
        gl16(gB0 + k0, &Bs[e0]);
        gl16(gB1 + k0, &Bs[e1]);
        __syncthreads();
        s16x8 af[4], bf[4];
        #pragma unroll
        for (int mi=0;mi<4;++mi) af[mi] = ldf(&As[(wm+mi*16+l15)*32 + quad*8]);
        #pragma unroll
        for (int ni=0;ni<4;++ni) bf[ni] = ldf(&Bs[(wn+ni*16+l15)*32 + quad*8]);
        #pragma unroll
        for (int mi=0;mi<4;++mi)
            #pragma unroll
            for (int ni=0;ni<4;++ni)
                acc[mi][ni] = __builtin_amdgcn_mfma_f32_16x16x32_bf16(af[mi], bf[ni], acc[mi][ni], 0,0,0);
    }

    #pragma unroll
    for (int mi=0;mi<4;++mi){
        const int m = m0 + wm + mi*16 + quad*4;
        #pragma unroll
        for (int ni=0;ni<4;++ni){
            const int n = n0 + wn + ni*16 + l15;
            #pragma unroll
            for (int r=0;r<4;++r)
                out[(size_t)(m+r)*CC + n] = acc[mi][ni][r];
        }
    }
}

extern "C" void kernel_launch(void* const* d_in, const int* in_sizes, int n_in,
                              void* d_out, int out_size, void* d_ws, size_t ws_size,
                              hipStream_t stream) {
    const float* x    = (const float*)d_in[0];
    const float* cosp = (const float*)d_in[1];
    const float* sinp = (const float*)d_in[2];
    const float* Wq   = (const float*)d_in[3];
    const float* Wk   = (const float*)d_in[4];
    const float* Wv   = (const float*)d_in[5];
    const float* Wo   = (const float*)d_in[6];

    u16t* ws  = (u16t*)d_ws;
    u16t* xb  = ws;                          // 8388608 elems (aliased by yws after qkv)
    u16t* wqb = xb  + 8388608;               // 4194304
    u16t* wkb = wqb + 4194304;               // 1048576
    u16t* wvb = wkb + 1048576;               // 1048576
    u16t* wob = wvb + 1048576;               // 4194304
    u16t* qws = wob + 4194304;               // 8388608
    u16t* kws = qws + 8388608;               // 2097152
    u16t* vtw = kws + 2097152;               // 2097152
    u16t* yws = xb;                          // alias: xb dead after qkv_kernel
    float* out = (float*)d_out;

    cvt_kernel<<<dim3(9216), 256, 0, stream>>>(x, Wq, Wk, Wv, Wo, xb, wqb, wkb, wvb, wob);
    qkv_kernel<<<dim3(32, 24), 256, 0, stream>>>(xb, wqb, wkb, wvb, cosp, sinp, qws, kws, vtw);
    attn_kernel<<<dim3(16, 16, 2), 256, 0, stream>>>(qws, kws, vtw, yws);
    oproj_kernel<<<dim3(32, 16), 256, 0, stream>>>(yws, wob, out);
}